// Round 1
// baseline (1667.721 us; speedup 1.0000x reference)
//
#include <hip/hip_runtime.h>

#define NB     64        // batch
#define NNODES 200000
#define NSTEPS 6
#define NEDGES 1000000
#define NIN    4096
#define NOUT   1024

// input phase: state[i][b] = tanh(x[b][i] * w_in[i] + bias[i]) for i < NIN
__global__ void input_kernel(const float* __restrict__ x,
                             const float* __restrict__ w_in,
                             const float* __restrict__ bias,
                             float* __restrict__ state) {
    int tid = blockIdx.x * blockDim.x + threadIdx.x;
    int i = tid >> 6;   // node
    int b = tid & 63;   // batch lane
    if (i < NIN) {
        float v = x[(size_t)b * NIN + i] * w_in[i] + bias[i];
        state[(size_t)i * NB + b] = tanhf(v);
    }
}

// one wave per edge (grid-stride): lane b handles batch element b
__global__ void edge_kernel(const float* __restrict__ w_edge,
                            const int* __restrict__ src,
                            const int* __restrict__ dst,
                            const float* __restrict__ state,
                            float* __restrict__ msg,
                            int* __restrict__ flag) {
    int lane = threadIdx.x & 63;
    int wid  = (int)((blockIdx.x * blockDim.x + threadIdx.x) >> 6);
    int nw   = (int)((gridDim.x * blockDim.x) >> 6);
    for (int e = wid; e < NEDGES; e += nw) {
        int eu = __builtin_amdgcn_readfirstlane(e);   // wave-uniform -> s_loads
        int s = src[eu];
        int d = dst[eu];
        float w = w_edge[eu];
        float v = w * state[(size_t)s * NB + lane];
        atomicAdd(&msg[(size_t)d * NB + lane], v);
        if (lane == 0) flag[d] = 1;
    }
}

// state = tanh(msg + bias + state) where flag; also re-zero msg/flag (fused)
__global__ void update_kernel(const float* __restrict__ bias,
                              float* __restrict__ state,
                              float* __restrict__ msg,
                              int* __restrict__ flag) {
    int tid = blockIdx.x * blockDim.x + threadIdx.x;
    int n = tid >> 6;
    int b = tid & 63;
    if (n >= NNODES) return;
    if (flag[n] == 0) return;
    size_t idx = (size_t)n * NB + b;
    float v = msg[idx] + bias[n] + state[idx];
    state[idx] = tanhf(v);
    msg[idx] = 0.f;
    if (b == 0) flag[n] = 0;
}

// out[b][j] = state[N - NOUT + j][b]
__global__ void output_kernel(const float* __restrict__ state,
                              float* __restrict__ out) {
    int tid = blockIdx.x * blockDim.x + threadIdx.x;
    if (tid >= NB * NOUT) return;
    int b = tid / NOUT;
    int j = tid % NOUT;
    out[tid] = state[(size_t)(NNODES - NOUT + j) * NB + b];
}

extern "C" void kernel_launch(void* const* d_in, const int* in_sizes, int n_in,
                              void* d_out, int out_size, void* d_ws, size_t ws_size,
                              hipStream_t stream) {
    const float* x      = (const float*)d_in[0];
    const float* w_in   = (const float*)d_in[1];
    const float* bias   = (const float*)d_in[2];
    const float* w_edge = (const float*)d_in[3];
    const int*   src    = (const int*)d_in[4];
    const int*   dst    = (const int*)d_in[5];
    float* out = (float*)d_out;

    float* state = (float*)d_ws;
    float* msg   = state + (size_t)NNODES * NB;
    int*   flag  = (int*)(msg + (size_t)NNODES * NB);

    // ws is poisoned 0xAA before every timed launch: zero our state
    hipMemsetAsync(state, 0, sizeof(float) * (size_t)NNODES * NB, stream);
    hipMemsetAsync(msg,   0, sizeof(float) * (size_t)NNODES * NB, stream);
    hipMemsetAsync(flag,  0, sizeof(int) * NNODES, stream);

    input_kernel<<<(NIN * 64 + 255) / 256, 256, 0, stream>>>(x, w_in, bias, state);

    const int eblocks = 8192;           // 32K waves, ~30 edges each (grid-stride)
    const int ublocks = (NNODES * 64 + 255) / 256;
    for (int s = 0; s < NSTEPS; ++s) {
        edge_kernel<<<eblocks, 256, 0, stream>>>(
            w_edge + (size_t)s * NEDGES, src + (size_t)s * NEDGES,
            dst + (size_t)s * NEDGES, state, msg, flag);
        update_kernel<<<ublocks, 256, 0, stream>>>(bias, state, msg, flag);
    }

    output_kernel<<<(NB * NOUT + 255) / 256, 256, 0, stream>>>(state, out);
}